// Round 19
// baseline (173.136 us; speedup 1.0000x reference)
//
#include <hip/hip_runtime.h>
#include <math.h>

#define BB 4
#define SS 2048
#define DD 1024
#define HH 16
#define HDD 64
#define NN (BB*SS)            // 8192 rows
#define WINDOWF 604800.0f     // 7 days
#define LOG2E 1.44269504088896340736f
#define SCALE2 (0.125f * LOG2E)   // 1/sqrt(64) * log2(e): scores in log2 domain
#define MSTATIC 24.0f             // static softmax shift (scores << 24; exact)

typedef __attribute__((ext_vector_type(8))) short bf16x8;
typedef __attribute__((ext_vector_type(4))) short bf16x4;
typedef __attribute__((ext_vector_type(4))) short s16x4;
typedef __attribute__((ext_vector_type(4))) float f32x4;

__device__ __forceinline__ unsigned short f2b(float f) {
    unsigned int x = __float_as_uint(f);
    unsigned int r = x + 0x7FFFu + ((x >> 16) & 1u);
    return (unsigned short)(r >> 16);
}

__device__ __forceinline__ unsigned int cvt_pk_bf16(float lo, float hi) {
    unsigned int r;
    asm("v_cvt_pk_bf16_f32 %0, %1, %2" : "=v"(r) : "v"(lo), "v"(hi));
    return r;
}

// async global->LDS, 16B per lane; LDS dest = wave-uniform base + lane*16
__device__ __forceinline__ void gload16(const unsigned short* g, unsigned short* l) {
    __builtin_amdgcn_global_load_lds(
        (const __attribute__((address_space(1))) unsigned int*)g,
        (__attribute__((address_space(3))) unsigned int*)l, 16, 0, 0);
}

// ---------------------------------------------------------------------------
// Fused f32->bf16 converts (32B/thread) + band_bounds + cs init.
// grid = 4096 (x) + 2048 (weights) + 32 (band) + 8 (cs) = 6184 blocks.
// ---------------------------------------------------------------------------
__global__ __launch_bounds__(256)
void cvt_band(const float* __restrict__ x,
              const float* __restrict__ Wq, const float* __restrict__ Wk,
              const float* __restrict__ Wv, const float* __restrict__ Wo,
              const float* __restrict__ ts, const float* __restrict__ bc,
              unsigned short* __restrict__ xb,
              unsigned short* __restrict__ Wqb, unsigned short* __restrict__ Wkb,
              unsigned short* __restrict__ Wvb, unsigned short* __restrict__ Wob,
              int* __restrict__ lo, int* __restrict__ hi,
              float* __restrict__ cs)
{
    const int g = blockIdx.x;
    const int tid = threadIdx.x;
    if (g < 6144) {
        const float* src; unsigned short* dst; int i;
        if (g < 4096) { src = x; dst = xb; i = g * 2048 + tid * 8; }
        else {
            const int wi = (g - 4096) >> 9;
            src = (wi == 0) ? Wq : (wi == 1) ? Wk : (wi == 2) ? Wv : Wo;
            dst = (wi == 0) ? Wqb : (wi == 1) ? Wkb : (wi == 2) ? Wvb : Wob;
            i = ((g - 4096) & 511) * 2048 + tid * 8;
        }
        float4 v0 = *(const float4*)(src + i);
        float4 v1 = *(const float4*)(src + i + 4);
        bf16x8 o;
        o[0] = (short)f2b(v0.x); o[1] = (short)f2b(v0.y);
        o[2] = (short)f2b(v0.z); o[3] = (short)f2b(v0.w);
        o[4] = (short)f2b(v1.x); o[5] = (short)f2b(v1.y);
        o[6] = (short)f2b(v1.z); o[7] = (short)f2b(v1.w);
        *(bf16x8*)(dst + i) = o;
    } else if (g < 6176) {
        const int idx = (g - 6144) * 256 + tid;   // 0..8191
        const int b = idx / SS, q = idx % SS;
        const float* t = ts + (size_t)b * SS;
        float tq = t[q];
        float lot = tq - WINDOWF - 1.0f;
        float hit = tq + WINDOWF + 1.0f;
        int l = 0, r = q;
        while (l < r) { int m = (l + r) >> 1; if (t[m] < lot) l = m + 1; else r = m; }
        lo[idx] = l;
        int l2 = q, r2 = SS - 1;
        while (l2 < r2) { int m = (l2 + r2 + 1) >> 1; if (t[m] > hit) r2 = m - 1; else l2 = m; }
        hi[idx] = l2;
    } else {
        // init change_scores to bc[0] (gemm_wo_change accumulates atomically)
        const int i = (g - 6176) * 1024 + tid * 4;
        const float b0 = bc[0];
        float4 v = {b0, b0, b0, b0};
        *(float4*)(cs + i) = v;
    }
}

// ---------------------------------------------------------------------------
// Shared m97-structure GEMM body: BK=64, global_load_lds w=16 staging with
// pre-swizzled SOURCE (chunk ^= row&7) + swizzled ds_read, 2-barrier K-loop.
// ---------------------------------------------------------------------------
__device__ __forceinline__
void gemm_core(const unsigned short* __restrict__ A,
               const unsigned short* __restrict__ Bw,
               int bm, int bn, int K,
               unsigned short* As, unsigned short* Bs, f32x4 (&acc)[4][4])
{
    constexpr int BK = 64;
    const int tid = threadIdx.x;
    const int wid = tid >> 6, l = tid & 63;
    const int wm = (wid >> 1) * 64, wn = (wid & 1) * 64;
    const int lr = l & 15, lg = l >> 4;

    const int srow = l >> 3;
    const int schunk = ((l & 7) ^ srow) * 8;

    for (int k0 = 0; k0 < K; k0 += BK) {
#pragma unroll
        for (int i = 0; i < 4; ++i) {
            const int r0 = wid * 32 + i * 8;
            gload16(A  + (size_t)(bm + r0 + srow) * K + k0 + schunk, &As[r0 * BK]);
            gload16(Bw + (size_t)(bn + r0 + srow) * K + k0 + schunk, &Bs[r0 * BK]);
        }
        __syncthreads();

#pragma unroll
        for (int ks = 0; ks < 2; ++ks) {
            bf16x8 af[4], bf[4];
#pragma unroll
            for (int am = 0; am < 4; ++am) {
                const int row = wm + am * 16 + lr;
                af[am] = *(const bf16x8*)&As[row * BK + (((ks * 4 + lg) ^ (row & 7)) * 8)];
            }
#pragma unroll
            for (int nf = 0; nf < 4; ++nf) {
                const int row = wn + nf * 16 + lr;
                bf[nf] = *(const bf16x8*)&Bs[row * BK + (((ks * 4 + lg) ^ (row & 7)) * 8)];
            }
#pragma unroll
            for (int am = 0; am < 4; ++am)
#pragma unroll
                for (int nf = 0; nf < 4; ++nf)
                    acc[am][nf] = __builtin_amdgcn_mfma_f32_16x16x32_bf16(
                        af[am], bf[nf], acc[am][nf], 0, 0, 0);
        }
        __syncthreads();
    }
}

// ---------------------------------------------------------------------------
// Fused Q+K projection (shared epilogue; uniform scalars only differ).
// ---------------------------------------------------------------------------
__global__ __launch_bounds__(256)
void gemm_qk(const unsigned short* __restrict__ xb,
             const unsigned short* __restrict__ Wqb,
             const unsigned short* __restrict__ Wkb,
             const float* __restrict__ bq, const float* __restrict__ bk,
             unsigned short* __restrict__ Qb, unsigned short* __restrict__ Kb2)
{
    __shared__ unsigned short As[128 * 64];
    __shared__ unsigned short Bs[128 * 64];

    const int seg = blockIdx.y >> 3;
    const int bm = blockIdx.x * 128;
    const int bn = (blockIdx.y & 7) * 128;
    const unsigned short* Bw = seg ? Wkb : Wqb;
    const float* bias = seg ? bk : bq;
    unsigned short* Y = seg ? Kb2 : Qb;
    const float alpha = seg ? 1.0f : SCALE2;

    f32x4 acc[4][4];
#pragma unroll
    for (int i = 0; i < 4; ++i)
#pragma unroll
        for (int j = 0; j < 4; ++j) acc[i][j] = (f32x4){0.f, 0.f, 0.f, 0.f};

    gemm_core(xb, Bw, bm, bn, DD, As, Bs, acc);

    const int l = threadIdx.x & 63, wid = threadIdx.x >> 6;
    const int wm = (wid >> 1) * 64, wn = (wid & 1) * 64;
    const int lr = l & 15, lg = l >> 4;
    float bia[4];
#pragma unroll
    for (int nf = 0; nf < 4; ++nf) bia[nf] = bias[bn + wn + nf * 16 + lr];

#pragma unroll
    for (int am = 0; am < 4; ++am)
#pragma unroll
        for (int nf = 0; nf < 4; ++nf)
#pragma unroll
            for (int r = 0; r < 4; ++r) {
                float o = (acc[am][nf][r] + bia[nf]) * alpha;
                size_t m = (size_t)(bm + wm + am * 16 + lg * 4 + r);
                size_t n = (size_t)(bn + wn + nf * 16 + lr);
                Y[m * DD + n] = f2b(o);
            }
}

// ---------------------------------------------------------------------------
// V projection with transposed Vt output [b][channel][s].
// ---------------------------------------------------------------------------
__global__ __launch_bounds__(256)
void gemm_v(const unsigned short* __restrict__ xb,
            const unsigned short* __restrict__ Wvb,
            const float* __restrict__ bv, unsigned short* __restrict__ Vtb)
{
    __shared__ unsigned short As[128 * 64];
    __shared__ unsigned short Bs[128 * 64];

    const int bm = blockIdx.x * 128;
    const int bn = blockIdx.y * 128;

    f32x4 acc[4][4];
#pragma unroll
    for (int i = 0; i < 4; ++i)
#pragma unroll
        for (int j = 0; j < 4; ++j) acc[i][j] = (f32x4){0.f, 0.f, 0.f, 0.f};

    gemm_core(xb, Wvb, bm, bn, DD, As, Bs, acc);

    const int l = threadIdx.x & 63, wid = threadIdx.x >> 6;
    const int wm = (wid >> 1) * 64, wn = (wid & 1) * 64;
    const int lr = l & 15, lg = l >> 4;
    float bia[4];
#pragma unroll
    for (int nf = 0; nf < 4; ++nf) bia[nf] = bv[bn + wn + nf * 16 + lr];

#pragma unroll
    for (int am = 0; am < 4; ++am)
#pragma unroll
        for (int nf = 0; nf < 4; ++nf) {
            int mbase = bm + wm + am * 16 + lg * 4;     // = b*SS + s_base
            int n = bn + wn + nf * 16 + lr;
            int bidx = mbase >> 11, sidx = mbase & (SS - 1);
            s16x4 o;
#pragma unroll
            for (int r = 0; r < 4; ++r)
                o[r] = (short)f2b(acc[am][nf][r] + bia[nf]);
            *(s16x4*)(Vtb + (((size_t)(bidx << 10) + n) << 11) + sidx) = o;
        }
}

// ---------------------------------------------------------------------------
// Wo projection (f32 out) with fused change-score epilogue.
// ---------------------------------------------------------------------------
__global__ __launch_bounds__(256)
void gemm_wo_change(const unsigned short* __restrict__ A,
                    const unsigned short* __restrict__ Bw,
                    const float* __restrict__ bias,
                    float* __restrict__ Y,
                    const float* __restrict__ Wc,
                    float* __restrict__ cs)
{
    __shared__ unsigned short As[128 * 64];
    __shared__ unsigned short Bs[128 * 64];

    const int bm = blockIdx.x * 128;
    const int bn = blockIdx.y * 128;

    f32x4 acc[4][4];
#pragma unroll
    for (int i = 0; i < 4; ++i)
#pragma unroll
        for (int j = 0; j < 4; ++j) acc[i][j] = (f32x4){0.f, 0.f, 0.f, 0.f};

    gemm_core(A, Bw, bm, bn, DD, As, Bs, acc);

    const int l = threadIdx.x & 63, wid = threadIdx.x >> 6;
    const int wm = (wid >> 1) * 64, wn = (wid & 1) * 64;
    const int lr = l & 15, lg = l >> 4;

    float bia[4], wcv[4];
#pragma unroll
    for (int nf = 0; nf < 4; ++nf) {
        bia[nf] = bias[bn + wn + nf * 16 + lr];
        wcv[nf] = Wc[bn + wn + nf * 16 + lr];
    }

    float csum[4][4];
#pragma unroll
    for (int am = 0; am < 4; ++am)
#pragma unroll
        for (int r = 0; r < 4; ++r) csum[am][r] = 0.f;

#pragma unroll
    for (int am = 0; am < 4; ++am)
#pragma unroll
        for (int nf = 0; nf < 4; ++nf)
#pragma unroll
            for (int r = 0; r < 4; ++r) {
                float o = acc[am][nf][r] + bia[nf];
                size_t m = (size_t)(bm + wm + am * 16 + lg * 4 + r);
                size_t n = (size_t)(bn + wn + nf * 16 + lr);
                Y[m * DD + n] = o;
                csum[am][r] = fmaf(o, wcv[nf], csum[am][r]);
            }

#pragma unroll
    for (int am = 0; am < 4; ++am)
#pragma unroll
        for (int r = 0; r < 4; ++r) {
            float v = csum[am][r];
            v += __shfl_xor(v, 1);
            v += __shfl_xor(v, 2);
            v += __shfl_xor(v, 4);
            v += __shfl_xor(v, 8);
            if (lr == 0)
                atomicAdd(&cs[bm + wm + am * 16 + lg * 4 + r], v);
        }
}

// ---------------------------------------------------------------------------
// MFMA flash attention, round-19: R16 template with 8-WAVE BLOCKS (512 thr,
// 128 q-rows/block).  Same LDS layout/dbuf/barriers/read-offsets/softmax;
// only the wave count and staging split change (each wave stages 8 rows =
// 1 gload16 per buffer).  Occupancy cap rises 20 -> 32 waves/CU (4 blocks
// x 8 waves, 128 KB LDS); staging bytes per band halve; grid = 1024 =
// exactly 4 blocks/CU (single dispatch round, no tail).
// ---------------------------------------------------------------------------
__global__ __launch_bounds__(512)
void attn_mfma(const unsigned short* __restrict__ Qb, const unsigned short* __restrict__ Kb,
               const unsigned short* __restrict__ Vt, const float* __restrict__ Tg,
               const int* __restrict__ lo, const int* __restrict__ hi,
               unsigned short* __restrict__ Ab)
{
    __shared__ unsigned short Ks[2][64 * 64];   // [key][dim], rotation-swizzled
    __shared__ unsigned short Vs[2][64 * 64];   // [dim][key], rotation-swizzled

    // XCD-aware decode + middle-out qt (longest bands first); 16 tiles of 128q
    const int blk = blockIdx.x;
    const int xcd = blk & 7;
    const int idx = blk >> 3;              // 0..127
    const int bh  = xcd * 8 + (idx >> 4);
    const int i4  = idx & 15;
    const int qt  = (i4 & 1) ? (7 - (i4 >> 1)) : (8 + (i4 >> 1));
    const int b = bh >> 4, h = bh & 15;

    const int tid = threadIdx.x;
    const int wid = tid >> 6, l = tid & 63;    // wid 0..7
    const int lr = l & 15, lg = l >> 4;
    const int q0w = qt * 128 + wid * 16;

    const size_t qrow = (size_t)(b * SS + q0w + lr);
    const bf16x8 qf0 = *(const bf16x8*)(Qb + qrow * DD + h * HDD + lg * 8);
    const bf16x8 qf1 = *(const bf16x8*)(Qb + qrow * DD + h * HDD + 32 + lg * 8);

    const float* tb = Tg + (size_t)b * SS;
    const float tq = tb[q0w + lr];
    const float tq_min = tb[qt * 128];
    const float tq_max = tb[qt * 128 + 127];

    const int t0 = lo[b * SS + qt * 128] >> 6;
    const int t1 = hi[b * SS + qt * 128 + 127] >> 6;

    const unsigned short* Kbh = Kb + (size_t)b * SS * DD + h * HDD;
    const unsigned short* Vth = Vt + ((size_t)(b * 1024 + h * HDD)) * SS;

    // staging lane map: slot p = l&7 holds chunk c = (p - row) & 7
    const int srow = l >> 3;                   // 0..7
    const int schunk = (((l & 7) - srow) & 7) * 8;

    // persistent staging pointers: wave wid stages rows wid*8 .. wid*8+7
    const unsigned short* kg0 = Kbh + (size_t)(t0 * 64 + wid * 8 + srow) * DD + schunk;
    const unsigned short* vg0 = Vth + (size_t)(wid * 8 + srow) * SS + t0 * 64 + schunk;

    // loop-invariant read offsets (elems), rotation p = (chunk + row) & 7
    const int ka_off = lr * 64 + (((lg + lr) & 7) << 3);     // QK row lr, chunk lg
    const int c0 = lg >> 1, h4 = (lg & 1) * 4;               // PV row lr (mod16)
    const int pv0 = lr * 64 + (((c0 + 0 + lr) & 7) << 3) + h4;
    const int pv1 = lr * 64 + (((c0 + 2 + lr) & 7) << 3) + h4;
    const int pv2 = lr * 64 + (((c0 + 4 + lr) & 7) << 3) + h4;
    const int pv3 = lr * 64 + (((c0 + 6 + lr) & 7) << 3) + h4;

    // ones A-frag for the l column-sum MFMA
    bf16x8 onesv;
#pragma unroll
    for (int j = 0; j < 8; ++j) onesv[j] = (short)0x3F80;

    unsigned short *Kc = &Ks[0][0], *Kn = &Ks[1][0];
    unsigned short *Vc = &Vs[0][0], *Vn = &Vs[1][0];

    float l_ = 0.f;
    f32x4 o_[4];
#pragma unroll
    for (int df = 0; df < 4; ++df) o_[df] = (f32x4){0.f, 0.f, 0.f, 0.f};

    // prologue: stage tile t0 into buffer 0 (wave wid -> rows wid*8..+7)
    gload16(kg0, Kc + wid * 512);
    gload16(vg0, Vc + wid * 512);
    kg0 += 64 * DD; vg0 += 64;
    __syncthreads();

    for (int t = t0; t <= t1; ++t) {
        const int kk0 = t * 64;

        // ---- issue next tile's staging into the other buffer ----
        if (t < t1) {
            gload16(kg0, Kn + wid * 512);
            gload16(vg0, Vn + wid * 512);
            kg0 += 64 * DD; vg0 += 64;
        }

        // ---- QK^T from LDS; accumulator seeded with -MSTATIC ----
        f32x4 s[4];
        __builtin_amdgcn_s_setprio(1);
#pragma unroll
        for (int kf = 0; kf < 4; ++kf) {
            bf16x8 ka0 = *(const bf16x8*)(Kc + kf * 1024 + ka_off);
            bf16x8 ka1 = *(const bf16x8*)(Kc + kf * 1024 + (ka_off ^ 32));
            f32x4 z = (f32x4){-MSTATIC, -MSTATIC, -MSTATIC, -MSTATIC};
            z = __builtin_amdgcn_mfma_f32_16x16x32_bf16(ka0, qf0, z, 0, 0, 0);
            z = __builtin_amdgcn_mfma_f32_16x16x32_bf16(ka1, qf1, z, 0, 0, 0);
            s[kf] = z;
        }
        __builtin_amdgcn_s_setprio(0);

        // ---- exact mask only on boundary tiles ----
        const bool needmask = !((tq_max - tb[kk0] <= WINDOWF - 4.0f) &&
                                (tb[kk0 + 63] - tq_min <= WINDOWF - 4.0f));
        if (needmask) {
#pragma unroll
            for (int kf = 0; kf < 4; ++kf) {
                float4 tk4 = *(const float4*)(tb + kk0 + kf * 16 + lg * 4);
                if (!(fabsf(tq - tk4.x) <= WINDOWF)) s[kf][0] = -INFINITY;
                if (!(fabsf(tq - tk4.y) <= WINDOWF)) s[kf][1] = -INFINITY;
                if (!(fabsf(tq - tk4.z) <= WINDOWF)) s[kf][2] = -INFINITY;
                if (!(fabsf(tq - tk4.w) <= WINDOWF)) s[kf][3] = -INFINITY;
            }
        }

        // ---- static-max softmax: p = exp2(s) directly ----
#pragma unroll
        for (int kf = 0; kf < 4; ++kf)
#pragma unroll
            for (int r = 0; r < 4; ++r)
                s[kf][r] = __builtin_amdgcn_exp2f(s[kf][r]);

        // ---- P^T -> packed bf16 (in-register) ----
        union { unsigned int u[4]; bf16x8 v; } pb[2];
#pragma unroll
        for (int c = 0; c < 2; ++c) {
            pb[c].u[0] = cvt_pk_bf16(s[2 * c][0],     s[2 * c][1]);
            pb[c].u[1] = cvt_pk_bf16(s[2 * c][2],     s[2 * c][3]);
            pb[c].u[2] = cvt_pk_bf16(s[2 * c + 1][0], s[2 * c + 1][1]);
            pb[c].u[3] = cvt_pk_bf16(s[2 * c + 1][2], s[2 * c + 1][3]);
        }

        // ---- l += column-sum of P via ones-MFMA (idle MFMA pipe) ----
        __builtin_amdgcn_s_setprio(1);
        {
            f32x4 zl = (f32x4){0.f, 0.f, 0.f, 0.f};
            zl = __builtin_amdgcn_mfma_f32_16x16x32_bf16(onesv, pb[0].v, zl, 0, 0, 0);
            zl = __builtin_amdgcn_mfma_f32_16x16x32_bf16(onesv, pb[1].v, zl, 0, 0, 0);
            l_ += zl[0];
        }

        // ---- O^T += V^T . P^T from LDS ----
#pragma unroll
        for (int df = 0; df < 4; ++df) {
            const int base = df * 1024;
            union { bf16x4 hh[2]; bf16x8 v; } va0, va1;
            va0.hh[0] = *(const bf16x4*)(Vc + base + pv0);
            va0.hh[1] = *(const bf16x4*)(Vc + base + pv1);
            va1.hh[0] = *(const bf16x4*)(Vc + base + pv2);
            va1.hh[1] = *(const bf16x4*)(Vc + base + pv3);
            o_[df] = __builtin_amdgcn_mfma_f32_16x16x32_bf16(va0.v, pb[0].v, o_[df], 0, 0, 0);
            o_[df] = __builtin_amdgcn_mfma_f32_16x16x32_bf16(va1.v, pb[1].v, o_[df], 0, 0, 0);
        }
        __builtin_amdgcn_s_setprio(0);

        __syncthreads();     // drains staging vmcnt; all reads of cur done
        unsigned short* tk = Kc; Kc = Kn; Kn = tk;
        unsigned short* tv = Vc; Vc = Vn; Vn = tv;
    }

    // finalize: attended[q][d] = O^T / l, packed 8B stores
    const float inv = 1.f / l_;
#pragma unroll
    for (int df = 0; df < 4; ++df) {
        s16x4 o;
#pragma unroll
        for (int r = 0; r < 4; ++r) o[r] = (short)f2b(o_[df][r] * inv);
        *(s16x4*)(Ab + qrow * DD + h * HDD + df * 16 + lg * 4) = o;
    }
}

// ---------------------------------------------------------------------------
extern "C" void kernel_launch(void* const* d_in, const int* in_sizes, int n_in,
                              void* d_out, int out_size, void* d_ws, size_t ws_size,
                              hipStream_t stream)
{
    (void)in_sizes; (void)n_in; (void)out_size; (void)ws_size;
    const float* x  = (const float*)d_in[0];
    const float* ts = (const float*)d_in[1];
    const float* Wq = (const float*)d_in[2];
    const float* bq = (const float*)d_in[3];
    const float* Wk = (const float*)d_in[4];
    const float* bk = (const float*)d_in[5];
    const float* Wv = (const float*)d_in[6];
    const float* bv = (const float*)d_in[7];
    const float* Wo = (const float*)d_in[8];
    const float* bo = (const float*)d_in[9];
    const float* Wc = (const float*)d_in[10];
    const float* bc = (const float*)d_in[11];

    float* out = (float*)d_out;                 // [N*D] output, then [N] change scores
    float* cs  = out + (size_t)NN * DD;

    unsigned short* xb  = (unsigned short*)d_ws;
    unsigned short* Qb  = xb  + (size_t)NN * DD;
    unsigned short* Kb2 = Qb  + (size_t)NN * DD;
    unsigned short* Vtb = Kb2 + (size_t)NN * DD;   // transposed [b][h*64+d][s]
    unsigned short* Abf = Vtb + (size_t)NN * DD;
    unsigned short* Wqb = Abf + (size_t)NN * DD;
    unsigned short* Wkb = Wqb + (size_t)DD * DD;
    unsigned short* Wvb = Wkb + (size_t)DD * DD;
    unsigned short* Wob = Wvb + (size_t)DD * DD;
    int* lo = (int*)(Wob + (size_t)DD * DD);
    int* hi = lo + NN;

    // fused converts + band bounds + cs init (one launch)
    cvt_band<<<6184, 256, 0, stream>>>(x, Wq, Wk, Wv, Wo, ts, bc,
                                       xb, Wqb, Wkb, Wvb, Wob, lo, hi, cs);

    // fused Q+K projections (one launch), V separate (transposed epilogue)
    gemm_qk<<<dim3(NN / 128, 16), 256, 0, stream>>>(xb, Wqb, Wkb, bq, bk, Qb, Kb2);
    gemm_v<<<dim3(NN / 128, DD / 128), 256, 0, stream>>>(xb, Wvb, bv, Vtb);

    attn_mfma<<<BB * HH * (SS / 128), 512, 0, stream>>>(Qb, Kb2, Vtb, ts, lo, hi, Abf);
    gemm_wo_change<<<dim3(NN / 128, DD / 128), 256, 0, stream>>>(Abf, Wob, bo, out, Wc, cs);
}

// Round 20
// 171.446 us; speedup vs baseline: 1.0099x; 1.0099x over previous
//
#include <hip/hip_runtime.h>
#include <math.h>

#define BB 4
#define SS 2048
#define DD 1024
#define HH 16
#define HDD 64
#define NN (BB*SS)            // 8192 rows
#define WINDOWF 604800.0f     // 7 days
#define LOG2E 1.44269504088896340736f
#define SCALE2 (0.125f * LOG2E)   // 1/sqrt(64) * log2(e): scores in log2 domain
#define MSTATIC 24.0f             // static softmax shift (scores << 24; exact)

typedef __attribute__((ext_vector_type(8))) short bf16x8;
typedef __attribute__((ext_vector_type(4))) short bf16x4;
typedef __attribute__((ext_vector_type(4))) short s16x4;
typedef __attribute__((ext_vector_type(4))) float f32x4;

__device__ __forceinline__ unsigned short f2b(float f) {
    unsigned int x = __float_as_uint(f);
    unsigned int r = x + 0x7FFFu + ((x >> 16) & 1u);
    return (unsigned short)(r >> 16);
}

__device__ __forceinline__ unsigned int cvt_pk_bf16(float lo, float hi) {
    unsigned int r;
    asm("v_cvt_pk_bf16_f32 %0, %1, %2" : "=v"(r) : "v"(lo), "v"(hi));
    return r;
}

// async global->LDS, 16B per lane; LDS dest = wave-uniform base + lane*16
__device__ __forceinline__ void gload16(const unsigned short* g, unsigned short* l) {
    __builtin_amdgcn_global_load_lds(
        (const __attribute__((address_space(1))) unsigned int*)g,
        (__attribute__((address_space(3))) unsigned int*)l, 16, 0, 0);
}

// ---------------------------------------------------------------------------
// Fused f32->bf16 converts (32B/thread) + band_bounds + cs init.
// grid = 4096 (x) + 2048 (weights) + 32 (band) + 8 (cs) = 6184 blocks.
// ---------------------------------------------------------------------------
__global__ __launch_bounds__(256)
void cvt_band(const float* __restrict__ x,
              const float* __restrict__ Wq, const float* __restrict__ Wk,
              const float* __restrict__ Wv, const float* __restrict__ Wo,
              const float* __restrict__ ts, const float* __restrict__ bc,
              unsigned short* __restrict__ xb,
              unsigned short* __restrict__ Wqb, unsigned short* __restrict__ Wkb,
              unsigned short* __restrict__ Wvb, unsigned short* __restrict__ Wob,
              int* __restrict__ lo, int* __restrict__ hi,
              float* __restrict__ cs)
{
    const int g = blockIdx.x;
    const int tid = threadIdx.x;
    if (g < 6144) {
        const float* src; unsigned short* dst; int i;
        if (g < 4096) { src = x; dst = xb; i = g * 2048 + tid * 8; }
        else {
            const int wi = (g - 4096) >> 9;
            src = (wi == 0) ? Wq : (wi == 1) ? Wk : (wi == 2) ? Wv : Wo;
            dst = (wi == 0) ? Wqb : (wi == 1) ? Wkb : (wi == 2) ? Wvb : Wob;
            i = ((g - 4096) & 511) * 2048 + tid * 8;
        }
        float4 v0 = *(const float4*)(src + i);
        float4 v1 = *(const float4*)(src + i + 4);
        bf16x8 o;
        o[0] = (short)f2b(v0.x); o[1] = (short)f2b(v0.y);
        o[2] = (short)f2b(v0.z); o[3] = (short)f2b(v0.w);
        o[4] = (short)f2b(v1.x); o[5] = (short)f2b(v1.y);
        o[6] = (short)f2b(v1.z); o[7] = (short)f2b(v1.w);
        *(bf16x8*)(dst + i) = o;
    } else if (g < 6176) {
        const int idx = (g - 6144) * 256 + tid;   // 0..8191
        const int b = idx / SS, q = idx % SS;
        const float* t = ts + (size_t)b * SS;
        float tq = t[q];
        float lot = tq - WINDOWF - 1.0f;
        float hit = tq + WINDOWF + 1.0f;
        int l = 0, r = q;
        while (l < r) { int m = (l + r) >> 1; if (t[m] < lot) l = m + 1; else r = m; }
        lo[idx] = l;
        int l2 = q, r2 = SS - 1;
        while (l2 < r2) { int m = (l2 + r2 + 1) >> 1; if (t[m] > hit) r2 = m - 1; else l2 = m; }
        hi[idx] = l2;
    } else {
        // init change_scores to bc[0] (gemm_wo_change accumulates atomically)
        const int i = (g - 6176) * 1024 + tid * 4;
        const float b0 = bc[0];
        float4 v = {b0, b0, b0, b0};
        *(float4*)(cs + i) = v;
    }
}

// ---------------------------------------------------------------------------
// Shared m97-structure GEMM body: BK=64, global_load_lds w=16 staging with
// pre-swizzled SOURCE (chunk ^= row&7) + swizzled ds_read, 2-barrier K-loop.
// ---------------------------------------------------------------------------
__device__ __forceinline__
void gemm_core(const unsigned short* __restrict__ A,
               const unsigned short* __restrict__ Bw,
               int bm, int bn, int K,
               unsigned short* As, unsigned short* Bs, f32x4 (&acc)[4][4])
{
    constexpr int BK = 64;
    const int tid = threadIdx.x;
    const int wid = tid >> 6, l = tid & 63;
    const int wm = (wid >> 1) * 64, wn = (wid & 1) * 64;
    const int lr = l & 15, lg = l >> 4;

    const int srow = l >> 3;
    const int schunk = ((l & 7) ^ srow) * 8;

    for (int k0 = 0; k0 < K; k0 += BK) {
#pragma unroll
        for (int i = 0; i < 4; ++i) {
            const int r0 = wid * 32 + i * 8;
            gload16(A  + (size_t)(bm + r0 + srow) * K + k0 + schunk, &As[r0 * BK]);
            gload16(Bw + (size_t)(bn + r0 + srow) * K + k0 + schunk, &Bs[r0 * BK]);
        }
        __syncthreads();

#pragma unroll
        for (int ks = 0; ks < 2; ++ks) {
            bf16x8 af[4], bf[4];
#pragma unroll
            for (int am = 0; am < 4; ++am) {
                const int row = wm + am * 16 + lr;
                af[am] = *(const bf16x8*)&As[row * BK + (((ks * 4 + lg) ^ (row & 7)) * 8)];
            }
#pragma unroll
            for (int nf = 0; nf < 4; ++nf) {
                const int row = wn + nf * 16 + lr;
                bf[nf] = *(const bf16x8*)&Bs[row * BK + (((ks * 4 + lg) ^ (row & 7)) * 8)];
            }
#pragma unroll
            for (int am = 0; am < 4; ++am)
#pragma unroll
                for (int nf = 0; nf < 4; ++nf)
                    acc[am][nf] = __builtin_amdgcn_mfma_f32_16x16x32_bf16(
                        af[am], bf[nf], acc[am][nf], 0, 0, 0);
        }
        __syncthreads();
    }
}

// ---------------------------------------------------------------------------
// Fused Q+K projection (shared epilogue; uniform scalars only differ).
// ---------------------------------------------------------------------------
__global__ __launch_bounds__(256)
void gemm_qk(const unsigned short* __restrict__ xb,
             const unsigned short* __restrict__ Wqb,
             const unsigned short* __restrict__ Wkb,
             const float* __restrict__ bq, const float* __restrict__ bk,
             unsigned short* __restrict__ Qb, unsigned short* __restrict__ Kb2)
{
    __shared__ unsigned short As[128 * 64];
    __shared__ unsigned short Bs[128 * 64];

    const int seg = blockIdx.y >> 3;
    const int bm = blockIdx.x * 128;
    const int bn = (blockIdx.y & 7) * 128;
    const unsigned short* Bw = seg ? Wkb : Wqb;
    const float* bias = seg ? bk : bq;
    unsigned short* Y = seg ? Kb2 : Qb;
    const float alpha = seg ? 1.0f : SCALE2;

    f32x4 acc[4][4];
#pragma unroll
    for (int i = 0; i < 4; ++i)
#pragma unroll
        for (int j = 0; j < 4; ++j) acc[i][j] = (f32x4){0.f, 0.f, 0.f, 0.f};

    gemm_core(xb, Bw, bm, bn, DD, As, Bs, acc);

    const int l = threadIdx.x & 63, wid = threadIdx.x >> 6;
    const int wm = (wid >> 1) * 64, wn = (wid & 1) * 64;
    const int lr = l & 15, lg = l >> 4;
    float bia[4];
#pragma unroll
    for (int nf = 0; nf < 4; ++nf) bia[nf] = bias[bn + wn + nf * 16 + lr];

#pragma unroll
    for (int am = 0; am < 4; ++am)
#pragma unroll
        for (int nf = 0; nf < 4; ++nf)
#pragma unroll
            for (int r = 0; r < 4; ++r) {
                float o = (acc[am][nf][r] + bia[nf]) * alpha;
                size_t m = (size_t)(bm + wm + am * 16 + lg * 4 + r);
                size_t n = (size_t)(bn + wn + nf * 16 + lr);
                Y[m * DD + n] = f2b(o);
            }
}

// ---------------------------------------------------------------------------
// V projection with transposed Vt output [b][channel][s].
// ---------------------------------------------------------------------------
__global__ __launch_bounds__(256)
void gemm_v(const unsigned short* __restrict__ xb,
            const unsigned short* __restrict__ Wvb,
            const float* __restrict__ bv, unsigned short* __restrict__ Vtb)
{
    __shared__ unsigned short As[128 * 64];
    __shared__ unsigned short Bs[128 * 64];

    const int bm = blockIdx.x * 128;
    const int bn = blockIdx.y * 128;

    f32x4 acc[4][4];
#pragma unroll
    for (int i = 0; i < 4; ++i)
#pragma unroll
        for (int j = 0; j < 4; ++j) acc[i][j] = (f32x4){0.f, 0.f, 0.f, 0.f};

    gemm_core(xb, Wvb, bm, bn, DD, As, Bs, acc);

    const int l = threadIdx.x & 63, wid = threadIdx.x >> 6;
    const int wm = (wid >> 1) * 64, wn = (wid & 1) * 64;
    const int lr = l & 15, lg = l >> 4;
    float bia[4];
#pragma unroll
    for (int nf = 0; nf < 4; ++nf) bia[nf] = bv[bn + wn + nf * 16 + lr];

#pragma unroll
    for (int am = 0; am < 4; ++am)
#pragma unroll
        for (int nf = 0; nf < 4; ++nf) {
            int mbase = bm + wm + am * 16 + lg * 4;     // = b*SS + s_base
            int n = bn + wn + nf * 16 + lr;
            int bidx = mbase >> 11, sidx = mbase & (SS - 1);
            s16x4 o;
#pragma unroll
            for (int r = 0; r < 4; ++r)
                o[r] = (short)f2b(acc[am][nf][r] + bia[nf]);
            *(s16x4*)(Vtb + (((size_t)(bidx << 10) + n) << 11) + sidx) = o;
        }
}

// ---------------------------------------------------------------------------
// Wo projection (f32 out) with fused change-score epilogue.
// ---------------------------------------------------------------------------
__global__ __launch_bounds__(256)
void gemm_wo_change(const unsigned short* __restrict__ A,
                    const unsigned short* __restrict__ Bw,
                    const float* __restrict__ bias,
                    float* __restrict__ Y,
                    const float* __restrict__ Wc,
                    float* __restrict__ cs)
{
    __shared__ unsigned short As[128 * 64];
    __shared__ unsigned short Bs[128 * 64];

    const int bm = blockIdx.x * 128;
    const int bn = blockIdx.y * 128;

    f32x4 acc[4][4];
#pragma unroll
    for (int i = 0; i < 4; ++i)
#pragma unroll
        for (int j = 0; j < 4; ++j) acc[i][j] = (f32x4){0.f, 0.f, 0.f, 0.f};

    gemm_core(A, Bw, bm, bn, DD, As, Bs, acc);

    const int l = threadIdx.x & 63, wid = threadIdx.x >> 6;
    const int wm = (wid >> 1) * 64, wn = (wid & 1) * 64;
    const int lr = l & 15, lg = l >> 4;

    float bia[4], wcv[4];
#pragma unroll
    for (int nf = 0; nf < 4; ++nf) {
        bia[nf] = bias[bn + wn + nf * 16 + lr];
        wcv[nf] = Wc[bn + wn + nf * 16 + lr];
    }

    float csum[4][4];
#pragma unroll
    for (int am = 0; am < 4; ++am)
#pragma unroll
        for (int r = 0; r < 4; ++r) csum[am][r] = 0.f;

#pragma unroll
    for (int am = 0; am < 4; ++am)
#pragma unroll
        for (int nf = 0; nf < 4; ++nf)
#pragma unroll
            for (int r = 0; r < 4; ++r) {
                float o = acc[am][nf][r] + bia[nf];
                size_t m = (size_t)(bm + wm + am * 16 + lg * 4 + r);
                size_t n = (size_t)(bn + wn + nf * 16 + lr);
                Y[m * DD + n] = o;
                csum[am][r] = fmaf(o, wcv[nf], csum[am][r]);
            }

#pragma unroll
    for (int am = 0; am < 4; ++am)
#pragma unroll
        for (int r = 0; r < 4; ++r) {
            float v = csum[am][r];
            v += __shfl_xor(v, 1);
            v += __shfl_xor(v, 2);
            v += __shfl_xor(v, 4);
            v += __shfl_xor(v, 8);
            if (lr == 0)
                atomicAdd(&cs[bm + wm + am * 16 + lg * 4 + r], v);
        }
}

// ---------------------------------------------------------------------------
// MFMA flash attention (R16/R18 verified best): 64q tiles, K+V dbuf
// gload_lds staging (rotation layout), static-max softmax (C-seed -MSTATIC),
// l via ones-MFMA, in-register P (cvt_pk), permuted-k PV, middle-out
// dispatch, XCD-aware decode.  16q per wave; 2-barrier-per-tile pipeline.
// Pinned at ~72us = LDS read-BW structural floor for this fragment layout
// (R12/R13/R17/R19 restructures all null or regressed).
// ---------------------------------------------------------------------------
__global__ __launch_bounds__(256)
void attn_mfma(const unsigned short* __restrict__ Qb, const unsigned short* __restrict__ Kb,
               const unsigned short* __restrict__ Vt, const float* __restrict__ Tg,
               const int* __restrict__ lo, const int* __restrict__ hi,
               unsigned short* __restrict__ Ab)
{
    __shared__ unsigned short Ks[2][64 * 64];   // [key][dim], rotation-swizzled
    __shared__ unsigned short Vs[2][64 * 64];   // [dim][key], rotation-swizzled

    // XCD-aware decode + middle-out qt (longest bands first)
    const int blk = blockIdx.x;
    const int xcd = blk & 7;
    const int idx = blk >> 3;              // 0..255
    const int bh  = xcd * 8 + (idx >> 5);
    const int i5  = idx & 31;
    const int qt  = (i5 & 1) ? (15 - (i5 >> 1)) : (16 + (i5 >> 1));
    const int b = bh >> 4, h = bh & 15;

    const int tid = threadIdx.x;
    const int wid = tid >> 6, l = tid & 63;
    const int lr = l & 15, lg = l >> 4;
    const int q0w = qt * 64 + wid * 16;

    const size_t qrow = (size_t)(b * SS + q0w + lr);
    const bf16x8 qf0 = *(const bf16x8*)(Qb + qrow * DD + h * HDD + lg * 8);
    const bf16x8 qf1 = *(const bf16x8*)(Qb + qrow * DD + h * HDD + 32 + lg * 8);

    const float* tb = Tg + (size_t)b * SS;
    const float tq = tb[q0w + lr];
    const float tq_min = tb[qt * 64];
    const float tq_max = tb[qt * 64 + 63];

    const int t0 = lo[b * SS + qt * 64] >> 6;
    const int t1 = hi[b * SS + qt * 64 + 63] >> 6;

    const unsigned short* Kbh = Kb + (size_t)b * SS * DD + h * HDD;
    const unsigned short* Vth = Vt + ((size_t)(b * 1024 + h * HDD)) * SS;

    // staging lane map: slot p = l&7 holds chunk c = (p - row) & 7
    const int srow = l >> 3;
    const int schunk = (((l & 7) - srow) & 7) * 8;

    // persistent staging pointers (advance by constant per tile)
    const unsigned short* kg0 = Kbh + (size_t)(t0 * 64 + wid * 16 + srow) * DD + schunk;
    const unsigned short* kg1 = kg0 + 8 * DD;
    const unsigned short* vg0 = Vth + (size_t)(wid * 16 + srow) * SS + t0 * 64 + schunk;
    const unsigned short* vg1 = vg0 + 8 * SS;

    // loop-invariant read offsets (elems), rotation p = (chunk + row) & 7
    const int ka_off = lr * 64 + (((lg + lr) & 7) << 3);     // QK row lr, chunk lg
    const int c0 = lg >> 1, h4 = (lg & 1) * 4;               // PV row lr (mod16)
    const int pv0 = lr * 64 + (((c0 + 0 + lr) & 7) << 3) + h4;
    const int pv1 = lr * 64 + (((c0 + 2 + lr) & 7) << 3) + h4;
    const int pv2 = lr * 64 + (((c0 + 4 + lr) & 7) << 3) + h4;
    const int pv3 = lr * 64 + (((c0 + 6 + lr) & 7) << 3) + h4;

    // ones A-frag for the l column-sum MFMA
    bf16x8 onesv;
#pragma unroll
    for (int j = 0; j < 8; ++j) onesv[j] = (short)0x3F80;

    unsigned short *Kc = &Ks[0][0], *Kn = &Ks[1][0];
    unsigned short *Vc = &Vs[0][0], *Vn = &Vs[1][0];

    float l_ = 0.f;
    f32x4 o_[4];
#pragma unroll
    for (int df = 0; df < 4; ++df) o_[df] = (f32x4){0.f, 0.f, 0.f, 0.f};

    // prologue: stage tile t0 into buffer 0
    gload16(kg0, Kc + wid * 1024);
    gload16(kg1, Kc + wid * 1024 + 512);
    gload16(vg0, Vc + wid * 1024);
    gload16(vg1, Vc + wid * 1024 + 512);
    kg0 += 64 * DD; kg1 += 64 * DD; vg0 += 64; vg1 += 64;
    __syncthreads();

    for (int t = t0; t <= t1; ++t) {
        const int kk0 = t * 64;

        // ---- issue next tile's staging into the other buffer ----
        if (t < t1) {
            gload16(kg0, Kn + wid * 1024);
            gload16(kg1, Kn + wid * 1024 + 512);
            gload16(vg0, Vn + wid * 1024);
            gload16(vg1, Vn + wid * 1024 + 512);
            kg0 += 64 * DD; kg1 += 64 * DD; vg0 += 64; vg1 += 64;
        }

        // ---- QK^T from LDS; accumulator seeded with -MSTATIC ----
        f32x4 s[4];
        __builtin_amdgcn_s_setprio(1);
#pragma unroll
        for (int kf = 0; kf < 4; ++kf) {
            bf16x8 ka0 = *(const bf16x8*)(Kc + kf * 1024 + ka_off);
            bf16x8 ka1 = *(const bf16x8*)(Kc + kf * 1024 + (ka_off ^ 32));
            f32x4 z = (f32x4){-MSTATIC, -MSTATIC, -MSTATIC, -MSTATIC};
            z = __builtin_amdgcn_mfma_f32_16x16x32_bf16(ka0, qf0, z, 0, 0, 0);
            z = __builtin_amdgcn_mfma_f32_16x16x32_bf16(ka1, qf1, z, 0, 0, 0);
            s[kf] = z;
        }
        __builtin_amdgcn_s_setprio(0);

        // ---- exact mask only on boundary tiles ----
        const bool needmask = !((tq_max - tb[kk0] <= WINDOWF - 4.0f) &&
                                (tb[kk0 + 63] - tq_min <= WINDOWF - 4.0f));
        if (needmask) {
#pragma unroll
            for (int kf = 0; kf < 4; ++kf) {
                float4 tk4 = *(const float4*)(tb + kk0 + kf * 16 + lg * 4);
                if (!(fabsf(tq - tk4.x) <= WINDOWF)) s[kf][0] = -INFINITY;
                if (!(fabsf(tq - tk4.y) <= WINDOWF)) s[kf][1] = -INFINITY;
                if (!(fabsf(tq - tk4.z) <= WINDOWF)) s[kf][2] = -INFINITY;
                if (!(fabsf(tq - tk4.w) <= WINDOWF)) s[kf][3] = -INFINITY;
            }
        }

        // ---- static-max softmax: p = exp2(s) directly ----
#pragma unroll
        for (int kf = 0; kf < 4; ++kf)
#pragma unroll
            for (int r = 0; r < 4; ++r)
                s[kf][r] = __builtin_amdgcn_exp2f(s[kf][r]);

        // ---- P^T -> packed bf16 (in-register) ----
        union { unsigned int u[4]; bf16x8 v; } pb[2];
#pragma unroll
        for (int c = 0; c < 2; ++c) {
            pb[c].u[0] = cvt_pk_bf16(s[2 * c][0],     s[2 * c][1]);
            pb[c].u[1] = cvt_pk_bf16(s[2 * c][2],     s[2 * c][3]);
            pb[c].u[2] = cvt_pk_bf16(s[2 * c + 1][0], s[2 * c + 1][1]);
            pb[c].u[3] = cvt_pk_bf16(s[2 * c + 1][2], s[2 * c + 1][3]);
        }

        // ---- l += column-sum of P via ones-MFMA (idle MFMA pipe) ----
        __builtin_amdgcn_s_setprio(1);
        {
            f32x4 zl = (f32x4){0.f, 0.f, 0.f, 0.f};
            zl = __builtin_amdgcn_mfma_f32_16x16x32_bf16(onesv, pb[0].v, zl, 0, 0, 0);
            zl = __builtin_amdgcn_mfma_f32_16x16x32_bf16(onesv, pb[1].v, zl, 0, 0, 0);
            l_ += zl[0];
        }

        // ---- O^T += V^T . P^T from LDS ----
#pragma unroll
        for (int df = 0; df < 4; ++df) {
            const int base = df * 1024;
            union { bf16x4 hh[2]; bf16x8 v; } va0, va1;
            va0.hh[0] = *(const bf16x4*)(Vc + base + pv0);
            va0.hh[1] = *(const bf16x4*)(Vc + base + pv1);
            va1.hh[0] = *(const bf16x4*)(Vc + base + pv2);
            va1.hh[1] = *(const bf16x4*)(Vc + base + pv3);
            o_[df] = __builtin_amdgcn_mfma_f32_16x16x32_bf16(va0.v, pb[0].v, o_[df], 0, 0, 0);
            o_[df] = __builtin_amdgcn_mfma_f32_16x16x32_bf16(va1.v, pb[1].v, o_[df], 0, 0, 0);
        }
        __builtin_amdgcn_s_setprio(0);

        __syncthreads();     // drains staging vmcnt; all reads of cur done
        unsigned short* tk = Kc; Kc = Kn; Kn = tk;
        unsigned short* tv = Vc; Vc = Vn; Vn = tv;
    }

    // finalize: attended[q][d] = O^T / l, packed 8B stores
    const float inv = 1.f / l_;
#pragma unroll
    for (int df = 0; df < 4; ++df) {
        s16x4 o;
#pragma unroll
        for (int r = 0; r < 4; ++r) o[r] = (short)f2b(o_[df][r] * inv);
        *(s16x4*)(Ab + qrow * DD + h * HDD + df * 16 + lg * 4) = o;
    }
}

// ---------------------------------------------------------------------------
extern "C" void kernel_launch(void* const* d_in, const int* in_sizes, int n_in,
                              void* d_out, int out_size, void* d_ws, size_t ws_size,
                              hipStream_t stream)
{
    (void)in_sizes; (void)n_in; (void)out_size; (void)ws_size;
    const float* x  = (const float*)d_in[0];
    const float* ts = (const float*)d_in[1];
    const float* Wq = (const float*)d_in[2];
    const float* bq = (const float*)d_in[3];
    const float* Wk = (const float*)d_in[4];
    const float* bk = (const float*)d_in[5];
    const float* Wv = (const float*)d_in[6];
    const float* bv = (const float*)d_in[7];
    const float* Wo = (const float*)d_in[8];
    const float* bo = (const float*)d_in[9];
    const float* Wc = (const float*)d_in[10];
    const float* bc = (const float*)d_in[11];

    float* out = (float*)d_out;                 // [N*D] output, then [N] change scores
    float* cs  = out + (size_t)NN * DD;

    unsigned short* xb  = (unsigned short*)d_ws;
    unsigned short* Qb  = xb  + (size_t)NN * DD;
    unsigned short* Kb2 = Qb  + (size_t)NN * DD;
    unsigned short* Vtb = Kb2 + (size_t)NN * DD;   // transposed [b][h*64+d][s]
    unsigned short* Abf = Vtb + (size_t)NN * DD;
    unsigned short* Wqb = Abf + (size_t)NN * DD;
    unsigned short* Wkb = Wqb + (size_t)DD * DD;
    unsigned short* Wvb = Wkb + (size_t)DD * DD;
    unsigned short* Wob = Wvb + (size_t)DD * DD;
    int* lo = (int*)(Wob + (size_t)DD * DD);
    int* hi = lo + NN;

    // fused converts + band bounds + cs init (one launch)
    cvt_band<<<6184, 256, 0, stream>>>(x, Wq, Wk, Wv, Wo, ts, bc,
                                       xb, Wqb, Wkb, Wvb, Wob, lo, hi, cs);

    // fused Q+K projections (one launch), V separate (transposed epilogue)
    gemm_qk<<<dim3(NN / 128, 16), 256, 0, stream>>>(xb, Wqb, Wkb, bq, bk, Qb, Kb2);
    gemm_v<<<dim3(NN / 128, DD / 128), 256, 0, stream>>>(xb, Wvb, bv, Vtb);

    attn_mfma<<<BB * HH * (SS / 64), 256, 0, stream>>>(Qb, Kb2, Vtb, ts, lo, hi, Abf);
    gemm_wo_change<<<dim3(NN / 128, DD / 128), 256, 0, stream>>>(Abf, Wob, bo, out, Wc, cs);
}